// Round 1
// 268.374 us; speedup vs baseline: 1.0224x; 1.0224x over previous
//
#include <hip/hip_runtime.h>
#include <hip/hip_bf16.h>

#define C_DIM 128
#define SCALE 0.17677669529663687f

typedef __attribute__((ext_vector_type(8))) short frag8;
typedef __attribute__((ext_vector_type(4))) float f32x4;

// ---- LDS (ushort units), 25216 total = 50432 B -> 3 blocks/CU ----
// Everything overlays one 25216-ushort arena:
//  * Staging phase: x as bf16 rows 0..48 (stride 136, 6800 ushorts at base 0).
//    xf frags are register-resident before barrier (2), so the arena is dead
//    as x after that barrier.
//  * Phase A..C: per-head wave-PRIVATE regions at h*6304 (head 0/1 overlay the
//    dead x staging):
//      Q 50x40 (row 49 trash), K 50x40, Vt 32x72 (cols 49..63 garbage,
//      cancelled by P zeros). P 50x72 (3600) overlays Q+K (4000) once qf/kf
//      are in regs.
//  * Phase D: act[tok][128ch] rows 0..49 stride 136 overlays head regions
//    (barrier (3) ensures all Phase C LDS reads retired first).
// Pad-token handling: reads clamp row to 48 (real, bounded); writes for pad
// tokens go to trash row 49; softmax guards j<49; P cols >=49 explicitly 0.
#define XACT_STR 136
#define HEAD_SZ  6304
#define KOFF 2000
#define VOFF 4000
#define Q_STR 40
#define VT_STR 72
#define P_STR 72
#define SMEM_TOT 25216

__device__ __forceinline__ unsigned short f2b(float x) {
    __hip_bfloat16 h = __float2bfloat16(x);
    return __builtin_bit_cast(unsigned short, h);
}
__device__ __forceinline__ unsigned pk2(float a, float b) {
    return ((unsigned)f2b(b) << 16) | (unsigned)f2b(a);
}

// fp32 weights -> bf16 ws: [0,49152) qkv_w, [49152,65536) proj_w
__global__ void convert_weights(const float4* __restrict__ qkvw,
                                const float4* __restrict__ projw,
                                ushort4* __restrict__ wbf) {
    int i = blockIdx.x * 256 + threadIdx.x;
    float4 v = (i < 12288) ? qkvw[i] : projw[i - 12288];
    ushort4 p;
    p.x = f2b(v.x); p.y = f2b(v.y); p.z = f2b(v.z); p.w = f2b(v.w);
    wbf[i] = p;
}

__global__ __launch_bounds__(256, 3) void attn_mfma(
    const float* __restrict__ x,
    const float* __restrict__ mask,
    const float* __restrict__ qkv_b,
    const float* __restrict__ proj_b,
    const unsigned short* __restrict__ wq,
    float* __restrict__ out)
{
    __shared__ __align__(16) unsigned short sm[SMEM_TOT];

    const int b = blockIdx.x, tid = threadIdx.x;
    const int h    = tid >> 6;   // wave = head, owns the full chain
    const int lane = tid & 63;
    const int n16  = lane & 15;
    const int q    = lane >> 4;

    // ---- hoisted proj weights + biases (overlap x staging latency) ----
    const unsigned short* pw = wq + 49152;
    frag8 wf2[2][4];
#pragma unroll
    for (int ct = 0; ct < 2; ++ct)
#pragma unroll
        for (int ks = 0; ks < 4; ++ks)
            wf2[ct][ks] = *(const frag8*)(pw + (size_t)(h * 32 + ct * 16 + n16) * C_DIM + ks * 32 + q * 8);
    float4 pb4[2];
#pragma unroll
    for (int ct = 0; ct < 2; ++ct)
        pb4[ct] = *(const float4*)(proj_b + h * 32 + ct * 16 + q * 4);

    // ---- stage x[b] rows 0..48 -> bf16 (base 0, stride 136) ----
    {
        const float4* xg = (const float4*)(x + (size_t)b * 6272);
        for (int i = tid; i < 1568; i += 256) {
            float4 v = xg[i];
            int row = i >> 5, col = (i & 31) << 2;
            uint2 pk; pk.x = pk2(v.x, v.y); pk.y = pk2(v.z, v.w);
            *(uint2*)&sm[row * XACT_STR + col] = pk;
        }
    }
    __syncthreads();  // (1) x staged

    // ---- x frags, pad rows clamp to row 48 ----
    frag8 xf[4][4];
#pragma unroll
    for (int tt = 0; tt < 4; ++tt)
#pragma unroll
        for (int ks = 0; ks < 4; ++ks)
            xf[tt][ks] = *(const frag8*)&sm[min(tt * 16 + n16, 48) * XACT_STR + ks * 32 + q * 8];
    __syncthreads();  // (2) x in regs everywhere -> head regions may overlay staging

    const int Hb = h * HEAD_SZ;

    // ---- Phase A: QKV, wave-private epilogues, NO barriers ----
#pragma unroll
    for (int mat = 0; mat < 3; ++mat) {
#pragma unroll
        for (int ct = 0; ct < 2; ++ct) {
            const unsigned short* wrow = wq + (size_t)(mat * C_DIM + h * 32 + ct * 16 + n16) * C_DIM;
            frag8 wf[4];
#pragma unroll
            for (int ks = 0; ks < 4; ++ks) wf[ks] = *(const frag8*)(wrow + ks * 32 + q * 8);
            if (mat < 2) {
                // D = W x^T: row=ch(q*4+r), col=tok(n16) -> Q/K[tok][ch] packed
                float4 b4 = *(const float4*)(qkv_b + mat * C_DIM + h * 32 + ct * 16 + q * 4);
                const float sc = (mat == 0) ? SCALE : 1.f;
                const int base = Hb + ((mat == 0) ? 0 : KOFF);
#pragma unroll
                for (int tt = 0; tt < 4; ++tt) {
                    f32x4 acc = {0.f, 0.f, 0.f, 0.f};
#pragma unroll
                    for (int ks = 0; ks < 4; ++ks)
                        acc = __builtin_amdgcn_mfma_f32_16x16x32_bf16(wf[ks], xf[tt][ks], acc, 0, 0, 0);
                    uint2 pk;
                    pk.x = pk2((acc[0] + b4.x) * sc, (acc[1] + b4.y) * sc);
                    pk.y = pk2((acc[2] + b4.z) * sc, (acc[3] + b4.w) * sc);
                    *(uint2*)&sm[base + min(tt * 16 + n16, 49) * Q_STR + ct * 16 + q * 4] = pk;
                }
            } else {
                // V: D = x W^T: row=tok(q*4+r), col=ch(n16) -> Vt[ch][tok] packed
                float bias = qkv_b[2 * C_DIM + h * 32 + ct * 16 + n16];
#pragma unroll
                for (int tt = 0; tt < 4; ++tt) {
                    f32x4 acc = {0.f, 0.f, 0.f, 0.f};
#pragma unroll
                    for (int ks = 0; ks < 4; ++ks)
                        acc = __builtin_amdgcn_mfma_f32_16x16x32_bf16(xf[tt][ks], wf[ks], acc, 0, 0, 0);
                    uint2 pk;
                    pk.x = pk2(acc[0] + bias, acc[1] + bias);
                    pk.y = pk2(acc[2] + bias, acc[3] + bias);
                    *(uint2*)&sm[Hb + VOFF + (ct * 16 + n16) * VT_STR + tt * 16 + q * 4] = pk;
                }
            }
        }
    }

    // ---- Phase B: S^T = K Q^T, mask (global fp32) as C-init; in-wave order ----
    frag8 qf[4], kf[4];
#pragma unroll
    for (int t = 0; t < 4; ++t) {
        qf[t] = *(const frag8*)&sm[Hb + (t * 16 + n16) * Q_STR + q * 8];
        kf[t] = *(const frag8*)&sm[Hb + KOFF + (t * 16 + n16) * Q_STR + q * 8];
    }
    const float* mrow = mask + (size_t)(b & 63) * 2401;
    f32x4 s[4][4];   // [jt][it]
#pragma unroll
    for (int it = 0; it < 4; ++it) {
        int ii = min(it * 16 + n16, 48);
#pragma unroll
        for (int jt = 0; jt < 3; ++jt) {
            const float* mp = mrow + ii * 49 + jt * 16 + q * 4;
            s[jt][it] = (f32x4){mp[0], mp[1], mp[2], mp[3]};
        }
        float m48 = (q == 0) ? mrow[ii * 49 + 48] : 0.f;
        s[3][it] = (f32x4){m48, 0.f, 0.f, 0.f};
    }
#pragma unroll
    for (int jt = 0; jt < 4; ++jt)
#pragma unroll
        for (int it = 0; it < 4; ++it)
            s[jt][it] = __builtin_amdgcn_mfma_f32_16x16x32_bf16(kf[jt], qf[it], s[jt][it], 0, 0, 0);

    // ---- softmax + P writes (P overlays Q+K; qf/kf already in regs) ----
#pragma unroll
    for (int it = 0; it < 4; ++it) {
        float mx = -1e30f;
#pragma unroll
        for (int jt = 0; jt < 4; ++jt)
#pragma unroll
            for (int r = 0; r < 4; ++r)
                if (jt * 16 + q * 4 + r < 49) mx = fmaxf(mx, s[jt][it][r]);
        mx = fmaxf(mx, __shfl_xor(mx, 16));
        mx = fmaxf(mx, __shfl_xor(mx, 32));
        float sum = 0.f;
#pragma unroll
        for (int jt = 0; jt < 4; ++jt)
#pragma unroll
            for (int r = 0; r < 4; ++r) {
                float e = (jt * 16 + q * 4 + r < 49) ? __expf(s[jt][it][r] - mx) : 0.f;
                s[jt][it][r] = e;
                sum += e;
            }
        sum += __shfl_xor(sum, 16);
        sum += __shfl_xor(sum, 32);
        float inv = __builtin_amdgcn_rcpf(sum);
#pragma unroll
        for (int jt = 0; jt < 4; ++jt) {
            uint2 pk;
            pk.x = pk2(s[jt][it][0] * inv, s[jt][it][1] * inv);
            pk.y = pk2(s[jt][it][2] * inv, s[jt][it][3] * inv);
            *(uint2*)&sm[Hb + min(it * 16 + n16, 49) * P_STR + jt * 16 + q * 4] = pk;
        }
    }

    // ---- Phase C: O^T = Vt P^T ----
    frag8 vf[2][2];
#pragma unroll
    for (int ct = 0; ct < 2; ++ct)
#pragma unroll
        for (int ks = 0; ks < 2; ++ks)
            vf[ct][ks] = *(const frag8*)&sm[Hb + VOFF + (ct * 16 + n16) * VT_STR + ks * 32 + q * 8];
    f32x4 o[2][4];
#pragma unroll
    for (int ct = 0; ct < 2; ++ct)
#pragma unroll
        for (int nt = 0; nt < 4; ++nt) o[ct][nt] = (f32x4){0.f, 0.f, 0.f, 0.f};
#pragma unroll
    for (int nt = 0; nt < 4; ++nt)
#pragma unroll
        for (int ks = 0; ks < 2; ++ks) {
            frag8 pf = *(const frag8*)&sm[Hb + min(nt * 16 + n16, 49) * P_STR + ks * 32 + q * 8];
#pragma unroll
            for (int ct = 0; ct < 2; ++ct)
                o[ct][nt] = __builtin_amdgcn_mfma_f32_16x16x32_bf16(vf[ct][ks], pf, o[ct][nt], 0, 0, 0);
        }
    __syncthreads();  // (3) all Phase C LDS reads retired -> act may overlay head regions

    // ---- act[tok][128ch] rows 0..49 stride 136 (row 49 = trash for pad toks) ----
#pragma unroll
    for (int ct = 0; ct < 2; ++ct)
#pragma unroll
        for (int nt = 0; nt < 4; ++nt) {
            uint2 pk;
            pk.x = pk2(o[ct][nt][0], o[ct][nt][1]);
            pk.y = pk2(o[ct][nt][2], o[ct][nt][3]);
            *(uint2*)&sm[min(nt * 16 + n16, 49) * XACT_STR + h * 32 + ct * 16 + q * 4] = pk;
        }
    __syncthreads();  // (4) act complete

    // ---- Phase D: out^T = W act^T -> float4 stores ----
    float* outb = out + (size_t)b * 6272;
#pragma unroll
    for (int nt = 0; nt < 4; ++nt) {
        frag8 af[4];
#pragma unroll
        for (int ks = 0; ks < 4; ++ks)
            af[ks] = *(const frag8*)&sm[min(nt * 16 + n16, 48) * XACT_STR + ks * 32 + q * 8];
        int tok = nt * 16 + n16;
#pragma unroll
        for (int ct = 0; ct < 2; ++ct) {
            f32x4 acc = {0.f, 0.f, 0.f, 0.f};
#pragma unroll
            for (int ks = 0; ks < 4; ++ks)
                acc = __builtin_amdgcn_mfma_f32_16x16x32_bf16(wf2[ct][ks], af[ks], acc, 0, 0, 0);
            if (tok < 49)
                *(float4*)&outb[tok * C_DIM + h * 32 + ct * 16 + q * 4] =
                    make_float4(acc[0] + pb4[ct].x, acc[1] + pb4[ct].y,
                                acc[2] + pb4[ct].z, acc[3] + pb4[ct].w);
        }
    }
}

extern "C" void kernel_launch(void* const* d_in, const int* in_sizes, int n_in,
                              void* d_out, int out_size, void* d_ws, size_t ws_size,
                              hipStream_t stream) {
    const float* x      = (const float*)d_in[0];
    const float* mask   = (const float*)d_in[1];
    const float* qkv_b  = (const float*)d_in[3];
    const float* proj_b = (const float*)d_in[5];

    unsigned short* wbf = (unsigned short*)d_ws;  // 131072 B
    convert_weights<<<64, 256, 0, stream>>>((const float4*)d_in[2],
                                            (const float4*)d_in[4],
                                            (ushort4*)wbf);
    attn_mfma<<<4096, 256, 0, stream>>>(x, mask, qkv_b, proj_b, wbf, (float*)d_out);
}